// Round 10
// baseline (438.481 us; speedup 1.0000x reference)
//
#include <hip/hip_runtime.h>

// B=16 E=128 W=256 HID=64 HOR=12
// row = b*128+e (2048 rows); one 64-lane wave per row in the scan.
// k_scan: 128 blocks x 1024 threads (16 rows/block), fence-free LLC protocol
// (HW-validated r6-r9): producers write panels/Eb with agent-scope sc0 sc1
// stores; per-b barrier = vmcnt(0) drain + relaxed agent atomicAdd + load
// spin; consumers stage panels into LDS via global_load_dwordx4 sc0 sc1.
// ROUND 10: the loop is LDS-BW + VALU bound (r9 arithmetic: ~96KB non-
// broadcast LDS reads/wave/step). gl/grT panels now BF16 (RTN): halves the
// GAT and ht LDS read phases, halves LLC staging traffic. Q/Eb/window
// recurrences stay fp32. k3+k4 merged into one kernel (grid split).

typedef __attribute__((ext_vector_type(4))) float f32x4;

struct Params {
  const float *__restrict__ x, *__restrict__ noise, *__restrict__ aw, *__restrict__ ab,
              *__restrict__ pe_w1, *__restrict__ pe_b1, *__restrict__ bn_g, *__restrict__ bn_b,
              *__restrict__ bn_m, *__restrict__ bn_v, *__restrict__ pe_w2, *__restrict__ pe_b2,
              *__restrict__ w1, *__restrict__ b1, *__restrict__ w2, *__restrict__ b2,
              *__restrict__ w3, *__restrict__ b3, *__restrict__ wl, *__restrict__ bl,
              *__restrict__ wr, *__restrict__ br, *__restrict__ attn, *__restrict__ out_w,
              *__restrict__ out_b, *__restrict__ ce_w, *__restrict__ ce_b, *__restrict__ cd_w,
              *__restrict__ cd_b, *__restrict__ q_w, *__restrict__ q_b, *__restrict__ k_w,
              *__restrict__ k_b;
  float* ws;
  float* out;
};

__device__ __forceinline__ float fast_tanh(float x) {
  float t = exp2f(fminf(2.8853900818f * x, 126.0f));   // exp(2x)
  return 1.0f - 2.0f * __builtin_amdgcn_rcpf(t + 1.0f);
}
__device__ __forceinline__ float fast_sigmoid(float x) {
  float t = exp2f(fminf(-1.44269504f * x, 126.0f));
  return __builtin_amdgcn_rcpf(1.0f + t);
}
__device__ __forceinline__ float wsum(float v) {
  #pragma unroll
  for (int m = 1; m < 64; m <<= 1) v += __shfl_xor(v, m, 64);
  return v;
}
__device__ __forceinline__ float wmax(float v) {
  #pragma unroll
  for (int m = 1; m < 64; m <<= 1) v = fmaxf(v, __shfl_xor(v, m, 64));
  return v;
}
// LLC-coherent (agent-scope, relaxed) access for cross-block traffic.
__device__ __forceinline__ float load_llc(const float* p) {
  return __hip_atomic_load(p, __ATOMIC_RELAXED, __HIP_MEMORY_SCOPE_AGENT);
}
__device__ __forceinline__ void store_llc(float* p, float v) {
  __hip_atomic_store(p, v, __ATOMIC_RELAXED, __HIP_MEMORY_SCOPE_AGENT);
}
__device__ __forceinline__ void store_llc_u32(unsigned* p, unsigned v) {
  __hip_atomic_store(p, v, __ATOMIC_RELAXED, __HIP_MEMORY_SCOPE_AGENT);
}
__device__ __forceinline__ f32x4 load_llc4(const void* p) {
  f32x4 v;
  asm volatile("global_load_dwordx4 %0, %1, off sc0 sc1" : "=v"(v) : "v"(p));
  return v;
}
__device__ __forceinline__ float load_llc1(const float* p) {
  float v;
  asm volatile("global_load_dword %0, %1, off sc0 sc1" : "=v"(v) : "v"(p));
  return v;
}
__device__ __forceinline__ void store_llc_u16(void* p, unsigned v) {
  asm volatile("global_store_short %0, %1, off sc0 sc1" :: "v"(p), "v"(v) : "memory");
}
// round-to-nearest bf16 (as low 16 bits)
__device__ __forceinline__ unsigned to_bf16(float f) {
  unsigned u = __float_as_uint(f);
  return (u + 0x7fffu + ((u >> 16) & 1u)) >> 16;
}
__device__ __forceinline__ float blo(unsigned w) { return __uint_as_float(w << 16); }
__device__ __forceinline__ float bhi(unsigned w) { return __uint_as_float(w & 0xffff0000u); }
// per-wave LDS write->read fence
__device__ __forceinline__ void lds_fence() {
  asm volatile("s_waitcnt lgkmcnt(0)" ::: "memory");
  __builtin_amdgcn_sched_barrier(0);
}

// workspace layout (float offsets). GL/GR regions oversized (bf16 uses half).
#define OFF_MS   0        // mean[16], std[16]
#define OFF_EB   32       // E coupling, double-buffered: 2 x 2048 (fp32)
#define OFF_CNT  4128     // 16 barrier counters, 32-int (128B) spacing
#define OFF_QV   16416    // q: 2048 x 32
#define OFF_KV   81952    // k: 2048 x 32
#define OFF_GL   147488   // gl bf16: 2 x [b: 16KB used of 32KB]  [j:128]x128B
#define OFF_GR   409632   // grT bf16: 2 x [b: 16KB used of 32KB] [f:64]x256B
#define OFF_H0   671776   // h0bn: 16 x 32 x 256
#define OFF_XW   802848   // window: 2048 x 272 (cols 0..255 used)
#define OFF_G    1359904  // G: 2048 x 272 (s in [0,253) used; read-only in scan)

// ---------- K1: per-b mean/std + h0 = bn(relu(conv5(xn))) ----------
__global__ __launch_bounds__(256)
void k1_h0(Params P) {
  __shared__ float red[8];
  const int tid = threadIdx.x, blk = blockIdx.x;
  const int idx = blk * 256 + tid;
  const int b = idx >> 13, c = (idx >> 8) & 31, w = idx & 255;
  const int lane = tid & 63, wv = tid >> 6;

  float v = P.x[b * 256 + w];
  float s = wsum(v), s2 = wsum(v * v);
  if (lane == 0) { red[wv] = s; red[4 + wv] = s2; }
  __syncthreads();
  float st  = red[0] + red[1] + red[2] + red[3];
  float st2 = red[4] + red[5] + red[6] + red[7];
  float mean = st * (1.f / 256.f);
  float var  = st2 * (1.f / 256.f) - mean * mean;
  float sd   = sqrtf(var);
  float* ms = P.ws + OFF_MS;
  if (tid == 0) { ms[b] = mean; ms[16 + b] = sd; }

  float rstd = 1.f / sd;
  float acc = P.pe_b1[c];
  #pragma unroll
  for (int k = 0; k < 5; k++) {
    int u = w - 2 + k;
    float xv = (u >= 0 && u < 256) ? (P.x[b * 256 + u] - mean) * rstd : 0.f;
    acc += P.pe_w1[c * 5 + k] * xv;
  }
  acc = fmaxf(acc, 0.f);
  float sc = P.bn_g[c] / sqrtf(P.bn_v[c] + 1e-5f);
  (P.ws + OFF_H0)[idx] = (acc - P.bn_m[c]) * sc + P.bn_b[c];
}

// ---------- K2: xf = affine(conv1x1(h0)) -> initial window ----------
__global__ __launch_bounds__(256)
void k2_xf(Params P) {
  const int idx = blockIdx.x * 256 + threadIdx.x;
  const int b = idx >> 15, e = (idx >> 8) & 127, w = idx & 255;
  const float* w2p  = P.pe_w2 + e * 32;
  const float* hcol = P.ws + OFF_H0 + b * 8192 + w;
  float acc = P.pe_b2[e];
  #pragma unroll 8
  for (int c = 0; c < 32; c++) acc += w2p[c] * hcol[c * 256];
  acc = acc * P.aw[e] + P.ab[e];
  (P.ws + OFF_XW)[(b * 128 + e) * 272 + w] = acc;
}

// ---------- K34: merged G-precompute (blocks 0..2047) + q,k proj (2048..2559) ----------
__global__ __launch_bounds__(256)
void k34(Params P) {
  if (blockIdx.x < 2048) {
    // k3 body: one block per row, one thread per s
    const int row = blockIdx.x;
    const int es  = row & 127;
    const int s   = threadIdx.x;
    const float* w1p = P.w1 + es * 128;
    const float* w2p = P.w2 + es * 512;
    const float* w3p = P.w3 + es * 64;
    const float* b1p = P.b1 + es * 64;
    const float* b2p = P.b2 + es * 64;
    const float  b3v = P.b3[es];
    const float* xr  = P.ws + OFF_XW + row * 272;
    if (s >= 253) return;
    float X0 = xr[s], X1 = xr[s + 1], X2 = xr[s + 2], X3 = xr[s + 3];
    float acc = 0.f;
    #pragma unroll 1
    for (int g2 = 0; g2 < 16; g2++) {
      float h1v[8];
      #pragma unroll
      for (int ic = 0; ic < 4; ic++) {
        int ch = g2 * 4 + ic;
        float ww0 = w1p[ch * 2], ww1 = w1p[ch * 2 + 1], bb = b1p[ch];
        h1v[ic * 2 + 0] = fast_tanh(bb + ww0 * X0 + ww1 * X1);
        h1v[ic * 2 + 1] = fast_tanh(bb + ww0 * X2 + ww1 * X3);
      }
      #pragma unroll
      for (int oc = 0; oc < 4; oc++) {
        int ch = g2 * 4 + oc;
        const float* wq = w2p + ch * 8;
        float a2 = b2p[ch];
        #pragma unroll
        for (int u = 0; u < 8; u++) a2 += wq[u] * h1v[u];
        acc += w3p[ch] * fast_tanh(a2);
      }
    }
    (P.ws + OFF_G)[row * 272 + s] = fast_tanh(b3v + acc);
  } else {
    // k4 body: q,k projections + barrier-counter zero
    const int gtid = (blockIdx.x - 2048) * 256 + threadIdx.x;
    if (gtid < 16) ((int*)(P.ws + OFF_CNT))[gtid * 32] = 0;
    const int half = gtid >> 16;
    const int idx  = gtid & 65535;
    const int row  = idx >> 5, h = idx & 31;
    const float* wm  = half ? P.k_w : P.q_w;
    const float* bv  = half ? P.k_b : P.q_b;
    const float* xr  = P.ws + OFF_XW + row * 272;
    const float* wrw = wm + h * 256;
    float acc = bv[h];
    #pragma unroll 8
    for (int w = 0; w < 256; w += 4) {
      float4 xx = *(const float4*)(xr + w);
      float4 wq = *(const float4*)(wrw + w);
      acc += xx.x * wq.x + xx.y * wq.y + xx.z * wq.z + xx.w * wq.w;
    }
    ((half ? P.ws + OFF_KV : P.ws + OFF_QV))[idx] = acc;
  }
}

// ---------- K_SCAN: adjacency + fence-free 12-step scan, bf16 panels ----------
__global__ __launch_bounds__(1024, 4)
void k_scan(Params P) {
  __shared__ __align__(16) char  glS[16384];     // bf16 [j:128] x 128B, XOR-swz chunks
  __shared__ __align__(16) char  grTS[16384];    // bf16 [f:64] x 256B, XOR-swz chunks
  __shared__ __align__(16) float WlS_[4096];     // fp32 [o:64] x 16 chunks, XOR-swz
  __shared__ __align__(16) float WrS_[4096];
  __shared__ __align__(16) float wscb[16 * 336]; // per wave: abuf128|hb64|h1b128|hist16
  __shared__ __align__(16) float attnS[64];
  const int tid = threadIdx.x, lane = tid & 63, wv = tid >> 6;
  const int row = blockIdx.x * 16 + wv;
  const int b = row >> 7, e = row & 127;
  float* ws = P.ws;
  float* abuf = wscb + wv * 336;
  float* hb   = abuf + 128;
  float* h1b  = abuf + 192;
  float* hist = abuf + 320;                // G[253+k] history (own row)
  const float4* hb4   = (const float4*)hb;
  const float4* abuf4 = (const float4*)abuf;
  const float4* attn4 = (const float4*)attnS;
  char* WlSc = (char*)WlS_;
  char* WrSc = (char*)WrS_;
  const float* grow_G = ws + OFF_G + row * 272;
  int* cntb = (int*)(ws + OFF_CNT) + b * 32;   // 8 blocks per b-group

  // stage Wl/Wr into LDS, swizzled (read-only weights, plain cached loads)
  {
    int o = tid >> 4, q = tid & 15;        // 1024 chunks exactly
    float4 vl = *(const float4*)(P.wl + o * 64 + q * 4);
    float4 vr = *(const float4*)(P.wr + o * 64 + q * 4);
    int off = o * 256 + ((q ^ (o & 15)) << 4);
    *(float4*)(WlSc + off) = vl;
    *(float4*)(WrSc + off) = vr;
  }
  if (tid < 64) attnS[tid] = P.attn[tid];

  // ---- per-lane invariants ----
  float cew0 = P.ce_w[lane * 3], cew1 = P.ce_w[lane * 3 + 1], cew2 = P.ce_w[lane * 3 + 2];
  float cebv = P.ce_b[lane];
  float cdw0 = P.cd_w[lane], cdw1 = P.cd_w[64 + lane], cdw2 = P.cd_w[128 + lane], cdw3 = P.cd_w[192 + lane];
  float cdb0 = P.cd_b[0], cdb1 = P.cd_b[1], cdb2 = P.cd_b[2], cdb3 = P.cd_b[3];
  float outw = P.out_w[e * 64 + lane], outb = P.out_b[e];
  float blv = P.bl[lane], brv = P.br[lane];
  float awv = P.aw[e], abv = P.ab[e];
  float meanb = ws[OFF_MS + b], stdb = ws[OFF_MS + 16 + b];
  float w10 = P.w1[e * 128 + lane * 2], w11 = P.w1[e * 128 + lane * 2 + 1];
  float b1v = P.b1[e * 64 + lane], b2v = P.b2[e * 64 + lane];
  float w3v = P.w3[e * 64 + lane], b3c = P.b3[e];
  float w2r[8];
  {
    const float4* w24 = (const float4*)(P.w2 + e * 512 + lane * 8);
    float4 a = w24[0], c = w24[1];
    w2r[0] = a.x; w2r[1] = a.y; w2r[2] = a.z; w2r[3] = a.w;
    w2r[4] = c.x; w2r[5] = c.y; w2r[6] = c.z; w2r[7] = c.w;
  }

  // ---- adjacency (folded k5): softmax over j of q.k, binarize ----
  bool a0b, a1b;
  {
    if (lane < 32) hb[lane] = (ws + OFF_QV)[row * 32 + lane];
    lds_fence();
    float e0, e1;
    #pragma unroll
    for (int half = 0; half < 2; half++) {
      int j = lane + half * 64;
      const float* kr = ws + OFF_KV + (b * 128 + j) * 32;
      float acc = 0.f;
      #pragma unroll
      for (int h = 0; h < 32; h += 4) {
        float4 kk = *(const float4*)(kr + h);
        float4 qq = *(const float4*)(hb + h);
        acc += qq.x * kk.x + qq.y * kk.y + qq.z * kk.z + qq.w * kk.w;
      }
      if (half == 0) e0 = acc; else e1 = acc;
    }
    float m   = wmax(fmaxf(e0, e1));
    float p0  = __expf(e0 - m), p1 = __expf(e1 - m);
    float inv = 1.f / wsum(p0 + p1);
    float av0 = p0 * inv, av1 = p1 * inv;
    P.out[38912 + row * 128 + lane]      = av0;
    P.out[38912 + row * 128 + lane + 64] = av1;
    a0b = av0 > 0.5f; a1b = av1 > 0.5f;
  }

  float h_own = grow_G[4 * lane];          // h(0)
  float xA = (ws + OFF_XW)[row * 272 + 253];
  float xB = (ws + OFF_XW)[row * 272 + 254];
  float xC = (ws + OFF_XW)[row * 272 + 255];
  float q0 = 1.f, q1 = 0.f, q2 = 0.f;
  if (lane == 0) store_llc(ws + OFF_EB + row, 0.f);   // E(0)=0, parity 0

  __syncthreads();   // WlS/WrS/attnS staged

  // ---- gl/gr(0) -> parity-0 bf16 panels, via LLC stores ----
  hb[lane] = h_own;
  lds_fence();
  float gri;
  {
    float glx = blv, grx = brv;
    const int k = lane & 15;
    #pragma unroll
    for (int q = 0; q < 16; q++) {
      float4 hq  = hb4[q];
      float4 wl4 = *(const float4*)(WlSc + lane * 256 + ((q ^ k) << 4));
      float4 wr4 = *(const float4*)(WrSc + lane * 256 + ((q ^ k) << 4));
      glx += hq.x * wl4.x + hq.y * wl4.y + hq.z * wl4.z + hq.w * wl4.w;
      grx += hq.x * wr4.x + hq.y * wr4.y + hq.z * wr4.z + hq.w * wr4.w;
    }
    char* glB  = (char*)(ws + OFF_GL) + b * 32768;   // [j:128] x 128B
    char* grTB = (char*)(ws + OFF_GR) + b * 32768;   // [f:64] x 256B
    unsigned ub = to_bf16(glx);
    unsigned pb = (unsigned)__shfl_xor((int)ub, 1, 64);
    if (!(lane & 1))
      store_llc_u32((unsigned*)(glB + e * 128) + (lane >> 1), ub | (pb << 16));
    store_llc_u16(grTB + lane * 256 + e * 2, to_bf16(grx));
    gri = grx;
  }

  #pragma unroll 1
  for (int t = 0; t < 12; t++) {
    // ---- per-b barrier (8 blocks): vmcnt drain + relaxed agent atomics ----
    asm volatile("s_waitcnt vmcnt(0)" ::: "memory");
    __syncthreads();
    if (tid == 0) {
      __hip_atomic_fetch_add(cntb, 1, __ATOMIC_RELAXED, __HIP_MEMORY_SCOPE_AGENT);
      const int target = (t + 1) * 8;
      while (__hip_atomic_load(cntb, __ATOMIC_RELAXED, __HIP_MEMORY_SCOPE_AGENT) < target)
        __builtin_amdgcn_s_sleep(2);
    }
    __syncthreads();

    const char* glG   = (const char*)(ws + OFF_GL + (t & 1) * 131072) + b * 32768;
    const char* grTG  = (const char*)(ws + OFF_GR + (t & 1) * 131072) + b * 32768;
    const float* EbO  = ws + OFF_EB + (t & 1) * 2048;
    float*       EbN  = ws + OFF_EB + ((t + 1) & 1) * 2048;
    char*        glGn  = (char*)(ws + OFF_GL + ((t + 1) & 1) * 131072) + b * 32768;
    char*        grTGn = (char*)(ws + OFF_GR + ((t + 1) & 1) * 131072) + b * 32768;

    // ---- issue cross-block loads: Eb(2 scalar), gl(1 x16B), grT(1 x16B) ----
    float ebv0 = load_llc1(EbO + b * 128 + lane);
    float ebv1 = load_llc1(EbO + b * 128 + lane + 64);
    const int jj = tid >> 3, jc = tid & 7;      // gl: 128 rows x 8 chunks
    const int ff = tid >> 4, fc = tid & 15;     // grT: 64 rows x 16 chunks
    f32x4 vg = load_llc4(glG  + jj * 128 + jc * 16);
    f32x4 vr = load_llc4(grTG + ff * 256 + fc * 16);

    // ---- gl ready at vmcnt(1) (only vr issued after it): write glS ----
    asm volatile("s_waitcnt vmcnt(1)" ::: "memory");
    __builtin_amdgcn_sched_barrier(0);
    *(f32x4*)(glS + jj * 128 + ((jc ^ (jj & 7)) << 4)) = vg;
    hb[lane] = gri;                        // own gr row fp32 (per-wave)
    asm volatile("s_waitcnt lgkmcnt(0)" ::: "memory");
    __builtin_amdgcn_sched_barrier(0);
    __builtin_amdgcn_s_barrier();          // glS visible block-wide

    // ---- GAT logits from bf16 glS; grT still in flight ----
    float ev0 = 0.f, ev1 = 0.f;
    {
      const char* r0 = glS + lane * 128;
      const char* r1 = glS + (lane + 64) * 128;  // (lane+64)&7 == lane&7
      const int k = lane & 7;
      #pragma unroll
      for (int c = 0; c < 8; c++) {
        float4 hqA = hb4[2 * c], hqB = hb4[2 * c + 1];
        float4 aqA = attn4[2 * c], aqB = attn4[2 * c + 1];
        int off = (c ^ k) << 4;
        uint4 g0 = *(const uint4*)(r0 + off);
        uint4 g1 = *(const uint4*)(r1 + off);
        float v;
        v = hqA.x + blo(g0.x); ev0 += fmaxf(v, 0.2f * v) * aqA.x;
        v = hqA.y + bhi(g0.x); ev0 += fmaxf(v, 0.2f * v) * aqA.y;
        v = hqA.z + blo(g0.y); ev0 += fmaxf(v, 0.2f * v) * aqA.z;
        v = hqA.w + bhi(g0.y); ev0 += fmaxf(v, 0.2f * v) * aqA.w;
        v = hqB.x + blo(g0.z); ev0 += fmaxf(v, 0.2f * v) * aqB.x;
        v = hqB.y + bhi(g0.z); ev0 += fmaxf(v, 0.2f * v) * aqB.y;
        v = hqB.z + blo(g0.w); ev0 += fmaxf(v, 0.2f * v) * aqB.z;
        v = hqB.w + bhi(g0.w); ev0 += fmaxf(v, 0.2f * v) * aqB.w;
        v = hqA.x + blo(g1.x); ev1 += fmaxf(v, 0.2f * v) * aqA.x;
        v = hqA.y + bhi(g1.x); ev1 += fmaxf(v, 0.2f * v) * aqA.y;
        v = hqA.z + blo(g1.y); ev1 += fmaxf(v, 0.2f * v) * aqA.z;
        v = hqA.w + bhi(g1.y); ev1 += fmaxf(v, 0.2f * v) * aqA.w;
        v = hqB.x + blo(g1.z); ev1 += fmaxf(v, 0.2f * v) * aqB.x;
        v = hqB.y + bhi(g1.z); ev1 += fmaxf(v, 0.2f * v) * aqB.y;
        v = hqB.z + blo(g1.w); ev1 += fmaxf(v, 0.2f * v) * aqB.z;
        v = hqB.w + bhi(g1.w); ev1 += fmaxf(v, 0.2f * v) * aqB.w;
      }
    }

    // ---- grT landed during GAT: write grTS, then softmax ----
    asm volatile("s_waitcnt vmcnt(0)" ::: "memory");
    __builtin_amdgcn_sched_barrier(0);
    *(f32x4*)(grTS + ff * 256 + ((fc ^ (ff & 15)) << 4)) = vr;

    ev0 = a0b ? ev0 : -1e20f;
    ev1 = a1b ? ev1 : -1e20f;
    float m   = wmax(fmaxf(ev0, ev1));
    float p0  = __expf(ev0 - m), p1 = __expf(ev1 - m);
    float inv = 1.f / wsum(p0 + p1);
    abuf[lane]      = p0 * inv;            // per-wave buffer
    abuf[lane + 64] = p1 * inv;
    __syncthreads();                       // grTS (block) + abuf (wave) ready

    // ---- h_temp[f=lane] = sum_j a[j] * gr[j][f] from bf16 grTS ----
    float ht = 0.f;
    {
      const char* rr = grTS + lane * 256;
      const int k = lane & 15;
      #pragma unroll
      for (int c = 0; c < 16; c++) {
        float4 aA = abuf4[2 * c], aB = abuf4[2 * c + 1];
        uint4 g = *(const uint4*)(rr + ((c ^ k) << 4));
        ht += aA.x * blo(g.x) + aA.y * bhi(g.x) + aA.z * blo(g.y) + aA.w * bhi(g.y)
            + aB.x * blo(g.z) + aB.y * bhi(g.z) + aB.z * blo(g.w) + aB.w * bhi(g.w);
      }
    }

    float hc = fast_tanh(cebv + q0 * cew0 + q1 * cew1 + q2 * cew2);
    float hf = h_own + fast_tanh(ht) + hc;

    float xp = wsum(hf * outw) + outb;
    float d0 = wsum(hf * cdw0);
    float d1 = wsum(hf * cdw1);
    float d2 = wsum(hf * cdw2);
    float d3 = wsum(hf * cdw3);
    float al = fast_sigmoid(d0 + cdb0);
    float be = fast_sigmoid(d1 + cdb1);
    float ga = fast_sigmoid(d2 + cdb2);
    float et = fast_sigmoid(d3 + cdb3);

    float ec = (a0b ? ebv0 : 0.f) + (a1b ? ebv1 : 0.f);
    ec = wsum(ec);

    float Hn = q0 - al * q0;
    float En = q1 + be * q0 - ga * q1 + 0.1f * ec;
    float Vn = q2 + et * q1 + P.noise[t * 2048 + row] * 0.01f;
    q0 = Hn; q1 = En; q2 = Vn;
    if (lane == 0) {
      store_llc(EbN + row, En);
      P.out[row * 12 + t] = (xp - abv) / awv * stdb + meanb;
      if (t == 11) {
        P.out[24576 + row * 3]     = Hn;
        P.out[24576 + row * 3 + 1] = En;
        P.out[24576 + row * 3 + 2] = Vn;
        P.out[30720 + row * 4]     = al;
        P.out[30720 + row * 4 + 1] = be;
        P.out[30720 + row * 4 + 2] = ga;
        P.out[30720 + row * 4 + 3] = et;
      }
    }

    if (t < 11) {
      // ---- incremental G: one new cnn column (window in registers) ----
      float X0 = xA, X1 = xB, X2 = xC, X3 = xp;
      xA = xB; xB = xC; xC = xp;
      float h1a = fast_tanh(b1v + w10 * X0 + w11 * X1);
      float h1c = fast_tanh(b1v + w10 * X2 + w11 * X3);
      h1b[lane * 2]     = h1a;             // per-wave buffer
      h1b[lane * 2 + 1] = h1c;
      lds_fence();
      const float* h1g = h1b + (lane >> 2) * 8;
      float a2 = b2v;
      #pragma unroll
      for (int u = 0; u < 8; u++) a2 += w2r[u] * h1g[u];
      float h2v = fast_tanh(a2);
      float g3  = wsum(w3v * h2v);
      float Gn  = fast_tanh(b3c + g3);
      if (lane == 0) hist[t] = Gn;         // own-row G history (per-wave LDS)

      // h(t+1): lane 63 fresh Gn; lanes whose index crossed 253 read history
      float hnext;
      if (lane == 63) {
        hnext = Gn;
      } else {
        int gi = (t + 1) + 4 * lane;
        hnext = (gi >= 253) ? hist[gi - 253] : grow_G[gi];
      }
      hb[lane] = hnext;                    // per-wave buffer
      lds_fence();
      float glx = blv, grx = brv;
      const int k = lane & 15;
      #pragma unroll
      for (int q = 0; q < 16; q++) {
        float4 hq  = hb4[q];
        float4 wl4 = *(const float4*)(WlSc + lane * 256 + ((q ^ k) << 4));
        float4 wr4 = *(const float4*)(WrSc + lane * 256 + ((q ^ k) << 4));
        glx += hq.x * wl4.x + hq.y * wl4.y + hq.z * wl4.z + hq.w * wl4.w;
        grx += hq.x * wr4.x + hq.y * wr4.y + hq.z * wr4.z + hq.w * wr4.w;
      }
      unsigned ub = to_bf16(glx);
      unsigned pb = (unsigned)__shfl_xor((int)ub, 1, 64);
      if (!(lane & 1))
        store_llc_u32((unsigned*)(glGn + e * 128) + (lane >> 1), ub | (pb << 16));
      store_llc_u16(grTGn + lane * 256 + e * 2, to_bf16(grx));
      gri = grx;
      h_own = hnext;
    }
  }
}

extern "C" void kernel_launch(void* const* d_in, const int* in_sizes, int n_in,
                              void* d_out, int out_size, void* d_ws, size_t ws_size,
                              hipStream_t stream) {
  Params p;
  p.x     = (const float*)d_in[0];  p.noise = (const float*)d_in[1];
  p.aw    = (const float*)d_in[2];  p.ab    = (const float*)d_in[3];
  p.pe_w1 = (const float*)d_in[4];  p.pe_b1 = (const float*)d_in[5];
  p.bn_g  = (const float*)d_in[6];  p.bn_b  = (const float*)d_in[7];
  p.bn_m  = (const float*)d_in[8];  p.bn_v  = (const float*)d_in[9];
  p.pe_w2 = (const float*)d_in[10]; p.pe_b2 = (const float*)d_in[11];
  p.w1    = (const float*)d_in[12]; p.b1    = (const float*)d_in[13];
  p.w2    = (const float*)d_in[14]; p.b2    = (const float*)d_in[15];
  p.w3    = (const float*)d_in[16]; p.b3    = (const float*)d_in[17];
  p.wl    = (const float*)d_in[18]; p.bl    = (const float*)d_in[19];
  p.wr    = (const float*)d_in[20]; p.br    = (const float*)d_in[21];
  p.attn  = (const float*)d_in[22]; p.out_w = (const float*)d_in[23];
  p.out_b = (const float*)d_in[24]; p.ce_w  = (const float*)d_in[25];
  p.ce_b  = (const float*)d_in[26]; p.cd_w  = (const float*)d_in[27];
  p.cd_b  = (const float*)d_in[28]; p.q_w   = (const float*)d_in[29];
  p.q_b   = (const float*)d_in[30]; p.k_w   = (const float*)d_in[31];
  p.k_b   = (const float*)d_in[32];
  p.ws  = (float*)d_ws;
  p.out = (float*)d_out;

  k1_h0<<<dim3(512),  dim3(256), 0, stream>>>(p);
  k2_xf<<<dim3(2048), dim3(256), 0, stream>>>(p);
  k34  <<<dim3(2560), dim3(256), 0, stream>>>(p);
  k_scan<<<dim3(128), dim3(1024), 0, stream>>>(p);
}

// Round 11
// 247.704 us; speedup vs baseline: 1.7702x; 1.7702x over previous
//
#include <hip/hip_runtime.h>

// B=16 E=128 W=256 HID=64 HOR=12
// row = b*128+e (2048 rows); one 64-lane wave per row in the scan.
// k_scan: PLAIN launch, 128 blocks x 1024 threads (16 rows/block), 2x CU
// slack for co-residency. FENCE-FREE cross-block protocol (HW-validated
// r6/r7): producers write gl/grT/Eb with relaxed AGENT atomic stores (fp32
// dword -- NEVER sub-dword: r10's bf16 short-stores caused partial-line RMW
// amplification at the LLC, 664MB HBM traffic, 2x regression); barrier =
// vmcnt(0) drain + relaxed agent atomicAdd + relaxed load spin; consumers
// stage panels into LDS via global_load_dwordx4 sc0 sc1.
// This round: REVERT to the round-7 kernel (best verified 263us, k_scan
// 181us) + merge k3/k4 into one launch (independent work, both only depend
// on k2; verified passing in r10).

typedef __attribute__((ext_vector_type(4))) float f32x4;

struct Params {
  const float *__restrict__ x, *__restrict__ noise, *__restrict__ aw, *__restrict__ ab,
              *__restrict__ pe_w1, *__restrict__ pe_b1, *__restrict__ bn_g, *__restrict__ bn_b,
              *__restrict__ bn_m, *__restrict__ bn_v, *__restrict__ pe_w2, *__restrict__ pe_b2,
              *__restrict__ w1, *__restrict__ b1, *__restrict__ w2, *__restrict__ b2,
              *__restrict__ w3, *__restrict__ b3, *__restrict__ wl, *__restrict__ bl,
              *__restrict__ wr, *__restrict__ br, *__restrict__ attn, *__restrict__ out_w,
              *__restrict__ out_b, *__restrict__ ce_w, *__restrict__ ce_b, *__restrict__ cd_w,
              *__restrict__ cd_b, *__restrict__ q_w, *__restrict__ q_b, *__restrict__ k_w,
              *__restrict__ k_b;
  float* ws;
  float* out;
};

__device__ __forceinline__ float fast_tanh(float x) {
  float t = exp2f(fminf(2.8853900818f * x, 126.0f));   // exp(2x)
  return 1.0f - 2.0f * __builtin_amdgcn_rcpf(t + 1.0f);
}
__device__ __forceinline__ float fast_sigmoid(float x) {
  float t = exp2f(fminf(-1.44269504f * x, 126.0f));
  return __builtin_amdgcn_rcpf(1.0f + t);
}
__device__ __forceinline__ float wsum(float v) {
  #pragma unroll
  for (int m = 1; m < 64; m <<= 1) v += __shfl_xor(v, m, 64);
  return v;
}
__device__ __forceinline__ float wmax(float v) {
  #pragma unroll
  for (int m = 1; m < 64; m <<= 1) v = fmaxf(v, __shfl_xor(v, m, 64));
  return v;
}
// LLC-coherent (agent-scope, relaxed) access for cross-block traffic.
__device__ __forceinline__ float load_llc(const float* p) {
  return __hip_atomic_load(p, __ATOMIC_RELAXED, __HIP_MEMORY_SCOPE_AGENT);
}
__device__ __forceinline__ void store_llc(float* p, float v) {
  __hip_atomic_store(p, v, __ATOMIC_RELAXED, __HIP_MEMORY_SCOPE_AGENT);
}
__device__ __forceinline__ f32x4 load_llc4(const float* p) {
  f32x4 v;
  asm volatile("global_load_dwordx4 %0, %1, off sc0 sc1" : "=v"(v) : "v"(p));
  return v;
}

// workspace layout (float offsets).
#define OFF_MS   0        // mean[16], std[16]
#define OFF_EB   32       // E coupling, double-buffered: 2 x 2048
#define OFF_CNT  4128     // 16 barrier counters, 32-int (128B) spacing
#define OFF_QV   16416    // q: 2048 x 32
#define OFF_KV   81952    // k: 2048 x 32
#define OFF_GL   147488   // gl: 2 x [b][j][f] = 2 x 2048 x 64
#define OFF_GR   409632   // grT: 2 x [b][f][j] = 2 x 16 x 64 x 128
#define OFF_H0   671776   // h0bn: 16 x 32 x 256
#define OFF_XW   802848   // window: 2048 x 272 (cols 0..255 used)
#define OFF_G    1359904  // G: 2048 x 272 (s in [0,253) used; read-only in scan)
#define OFF_ADJ  1916960  // adj_bin: 2048 x 128 uint8

// ---------- K1: per-b mean/std + h0 = bn(relu(conv5(xn))) ----------
__global__ __launch_bounds__(256)
void k1_h0(Params P) {
  __shared__ float red[8];
  const int tid = threadIdx.x, blk = blockIdx.x;
  const int idx = blk * 256 + tid;
  const int b = idx >> 13, c = (idx >> 8) & 31, w = idx & 255;
  const int lane = tid & 63, wv = tid >> 6;

  float v = P.x[b * 256 + w];
  float s = wsum(v), s2 = wsum(v * v);
  if (lane == 0) { red[wv] = s; red[4 + wv] = s2; }
  __syncthreads();
  float st  = red[0] + red[1] + red[2] + red[3];
  float st2 = red[4] + red[5] + red[6] + red[7];
  float mean = st * (1.f / 256.f);
  float var  = st2 * (1.f / 256.f) - mean * mean;
  float sd   = sqrtf(var);
  float* ms = P.ws + OFF_MS;
  if (tid == 0) { ms[b] = mean; ms[16 + b] = sd; }

  float rstd = 1.f / sd;
  float acc = P.pe_b1[c];
  #pragma unroll
  for (int k = 0; k < 5; k++) {
    int u = w - 2 + k;
    float xv = (u >= 0 && u < 256) ? (P.x[b * 256 + u] - mean) * rstd : 0.f;
    acc += P.pe_w1[c * 5 + k] * xv;
  }
  acc = fmaxf(acc, 0.f);
  float sc = P.bn_g[c] / sqrtf(P.bn_v[c] + 1e-5f);
  (P.ws + OFF_H0)[idx] = (acc - P.bn_m[c]) * sc + P.bn_b[c];
}

// ---------- K2: xf = affine(conv1x1(h0)) -> initial window ----------
__global__ __launch_bounds__(256)
void k2_xf(Params P) {
  const int idx = blockIdx.x * 256 + threadIdx.x;
  const int b = idx >> 15, e = (idx >> 8) & 127, w = idx & 255;
  const float* w2p  = P.pe_w2 + e * 32;
  const float* hcol = P.ws + OFF_H0 + b * 8192 + w;
  float acc = P.pe_b2[e];
  #pragma unroll 8
  for (int c = 0; c < 32; c++) acc += w2p[c] * hcol[c * 256];
  acc = acc * P.aw[e] + P.ab[e];
  (P.ws + OFF_XW)[(b * 128 + e) * 272 + w] = acc;
}

// ---------- K34: merged G-precompute (blocks 0..2047) + q,k proj (2048..2559) ----------
__global__ __launch_bounds__(256)
void k34(Params P) {
  if (blockIdx.x < 2048) {
    // k3 body: one block per row, one thread per s
    const int row = blockIdx.x;
    const int es  = row & 127;
    const int s   = threadIdx.x;
    const float* w1p = P.w1 + es * 128;
    const float* w2p = P.w2 + es * 512;
    const float* w3p = P.w3 + es * 64;
    const float* b1p = P.b1 + es * 64;
    const float* b2p = P.b2 + es * 64;
    const float  b3v = P.b3[es];
    const float* xr  = P.ws + OFF_XW + row * 272;
    if (s >= 253) return;
    float X0 = xr[s], X1 = xr[s + 1], X2 = xr[s + 2], X3 = xr[s + 3];
    float acc = 0.f;
    #pragma unroll 1
    for (int g2 = 0; g2 < 16; g2++) {
      float h1v[8];
      #pragma unroll
      for (int ic = 0; ic < 4; ic++) {
        int ch = g2 * 4 + ic;
        float ww0 = w1p[ch * 2], ww1 = w1p[ch * 2 + 1], bb = b1p[ch];
        h1v[ic * 2 + 0] = fast_tanh(bb + ww0 * X0 + ww1 * X1);
        h1v[ic * 2 + 1] = fast_tanh(bb + ww0 * X2 + ww1 * X3);
      }
      #pragma unroll
      for (int oc = 0; oc < 4; oc++) {
        int ch = g2 * 4 + oc;
        const float* wq = w2p + ch * 8;
        float a2 = b2p[ch];
        #pragma unroll
        for (int u = 0; u < 8; u++) a2 += wq[u] * h1v[u];
        acc += w3p[ch] * fast_tanh(a2);
      }
    }
    (P.ws + OFF_G)[row * 272 + s] = fast_tanh(b3v + acc);
  } else {
    // k4 body: q,k projections + barrier-counter zero
    const int gtid = (blockIdx.x - 2048) * 256 + threadIdx.x;
    if (gtid < 16) ((int*)(P.ws + OFF_CNT))[gtid * 32] = 0;
    const int half = gtid >> 16;
    const int idx  = gtid & 65535;
    const int row  = idx >> 5, h = idx & 31;
    const float* wm  = half ? P.k_w : P.q_w;
    const float* bv  = half ? P.k_b : P.q_b;
    const float* xr  = P.ws + OFF_XW + row * 272;
    const float* wrw = wm + h * 256;
    float acc = bv[h];
    #pragma unroll 8
    for (int w = 0; w < 256; w += 4) {
      float4 xx = *(const float4*)(xr + w);
      float4 wq = *(const float4*)(wrw + w);
      acc += xx.x * wq.x + xx.y * wq.y + xx.z * wq.z + xx.w * wq.w;
    }
    ((half ? P.ws + OFF_KV : P.ws + OFF_QV))[idx] = acc;
  }
}

// ---------- K5: adjacency softmax + binarize ----------
__global__ __launch_bounds__(256)
void k5_adj(Params P) {
  __shared__ __align__(16) float hbuf[4 * 64];
  const int tid = threadIdx.x, lane = tid & 63, wv = tid >> 6;
  const int row = blockIdx.x * 4 + wv;
  const int b = row >> 7;
  float* ws = P.ws;
  float* hb = hbuf + wv * 64;
  unsigned char* adjb = (unsigned char*)(ws + OFF_ADJ);

  if (lane < 32) hb[lane] = (ws + OFF_QV)[row * 32 + lane];
  __syncthreads();
  float ev0, ev1;
  #pragma unroll
  for (int half = 0; half < 2; half++) {
    int j = lane + half * 64;
    const float* kr = ws + OFF_KV + (b * 128 + j) * 32;
    float acc = 0.f;
    #pragma unroll
    for (int h = 0; h < 32; h += 4) {
      float4 kk = *(const float4*)(kr + h);
      float4 qq = *(const float4*)(hb + h);
      acc += qq.x * kk.x + qq.y * kk.y + qq.z * kk.z + qq.w * kk.w;
    }
    if (half == 0) ev0 = acc; else ev1 = acc;
  }
  float m   = wmax(fmaxf(ev0, ev1));
  float p0  = __expf(ev0 - m), p1 = __expf(ev1 - m);
  float inv = 1.f / wsum(p0 + p1);
  float a0 = p0 * inv, a1 = p1 * inv;
  P.out[38912 + row * 128 + lane]      = a0;
  P.out[38912 + row * 128 + lane + 64] = a1;
  adjb[row * 128 + lane]      = (a0 > 0.5f) ? 1 : 0;
  adjb[row * 128 + lane + 64] = (a1 > 0.5f) ? 1 : 0;
}

// ---------- K_SCAN: fence-free 12-step scan, 128 blocks x 1024 threads ----------
__global__ __launch_bounds__(1024, 4)
void k_scan(Params P) {
  __shared__ __align__(16) float glS_[8192];     // 32KB: [j:128] x 16 chunks, XOR-swz
  __shared__ __align__(16) float grTS_[8192];    // 32KB: [f:64] x 32 chunks, XOR-swz
  __shared__ __align__(16) float WlS_[4096];     // 16KB: [o:64] x 16 chunks, XOR-swz
  __shared__ __align__(16) float WrS_[4096];
  __shared__ __align__(16) float wscb[16 * 336]; // per wave: abuf128|hb64|h1b128|hist16
  __shared__ __align__(16) float attnS[64];
  const int tid = threadIdx.x, lane = tid & 63, wv = tid >> 6;
  const int row = blockIdx.x * 16 + wv;
  const int b = row >> 7, e = row & 127;
  float* ws = P.ws;
  float* abuf = wscb + wv * 336;
  float* hb   = abuf + 128;
  float* h1b  = abuf + 192;
  float* hist = abuf + 320;                // G[253+k] history (own row)
  const float4* hb4   = (const float4*)hb;
  const float4* abuf4 = (const float4*)abuf;
  const float4* attn4 = (const float4*)attnS;
  char* glS  = (char*)glS_;
  char* grTS = (char*)grTS_;
  char* WlSc = (char*)WlS_;
  char* WrSc = (char*)WrS_;
  const float* grow_G = ws + OFF_G + row * 272;
  const unsigned char* arow = (const unsigned char*)(ws + OFF_ADJ) + row * 128;
  int* cntb = (int*)(ws + OFF_CNT) + b * 32;   // 8 blocks per b-group

  // stage Wl/Wr rows into LDS, swizzled (weights constant -> plain loads)
  {
    int o = tid >> 4, q = tid & 15;        // 1024 chunks exactly
    float4 vl = *(const float4*)(P.wl + o * 64 + q * 4);
    float4 vr = *(const float4*)(P.wr + o * 64 + q * 4);
    int off = o * 256 + ((q ^ (o & 15)) << 4);
    *(float4*)(WlSc + off) = vl;
    *(float4*)(WrSc + off) = vr;
  }
  if (tid < 64) attnS[tid] = P.attn[tid];

  // ---- per-lane invariants ----
  float cew0 = P.ce_w[lane * 3], cew1 = P.ce_w[lane * 3 + 1], cew2 = P.ce_w[lane * 3 + 2];
  float cebv = P.ce_b[lane];
  float cdw0 = P.cd_w[lane], cdw1 = P.cd_w[64 + lane], cdw2 = P.cd_w[128 + lane], cdw3 = P.cd_w[192 + lane];
  float cdb0 = P.cd_b[0], cdb1 = P.cd_b[1], cdb2 = P.cd_b[2], cdb3 = P.cd_b[3];
  float outw = P.out_w[e * 64 + lane], outb = P.out_b[e];
  float blv = P.bl[lane], brv = P.br[lane];
  float awv = P.aw[e], abv = P.ab[e];
  float meanb = ws[OFF_MS + b], stdb = ws[OFF_MS + 16 + b];
  float w10 = P.w1[e * 128 + lane * 2], w11 = P.w1[e * 128 + lane * 2 + 1];
  float b1v = P.b1[e * 64 + lane], b2v = P.b2[e * 64 + lane];
  float w3v = P.w3[e * 64 + lane], b3c = P.b3[e];
  float w2r[8];
  {
    const float4* w24 = (const float4*)(P.w2 + e * 512 + lane * 8);
    float4 a = w24[0], c = w24[1];
    w2r[0] = a.x; w2r[1] = a.y; w2r[2] = a.z; w2r[3] = a.w;
    w2r[4] = c.x; w2r[5] = c.y; w2r[6] = c.z; w2r[7] = c.w;
  }
  const bool a0b = arow[lane] != 0, a1b = arow[lane + 64] != 0;
  float h_own = grow_G[4 * lane];          // h(0)
  float xA = (ws + OFF_XW)[row * 272 + 253];
  float xB = (ws + OFF_XW)[row * 272 + 254];
  float xC = (ws + OFF_XW)[row * 272 + 255];
  float q0 = 1.f, q1 = 0.f, q2 = 0.f;
  if (lane == 0) store_llc(ws + OFF_EB + row, 0.f);   // E(0)=0, parity 0

  __syncthreads();   // W/attn staged

  // ---- gl/gr(0) -> parity-0, via LLC stores ----
  hb[lane] = h_own;
  __syncthreads();
  float gri;
  {
    float glx = blv, grx = brv;
    const int k = lane & 15;
    #pragma unroll
    for (int q = 0; q < 16; q++) {
      float4 hq  = hb4[q];
      float4 wl4 = *(const float4*)(WlSc + lane * 256 + ((q ^ k) << 4));
      float4 wr4 = *(const float4*)(WrSc + lane * 256 + ((q ^ k) << 4));
      glx += hq.x * wl4.x + hq.y * wl4.y + hq.z * wl4.z + hq.w * wl4.w;
      grx += hq.x * wr4.x + hq.y * wr4.y + hq.z * wr4.z + hq.w * wr4.w;
    }
    store_llc(ws + OFF_GL + row * 64 + lane, glx);
    store_llc(ws + OFF_GR + b * 8192 + lane * 128 + e, grx);
    gri = grx;
  }

  // precomputed staging indices (invariant over t)
  const int jj0 = tid >> 4,          cc0 = tid & 15;          // gl chunk A
  const int jj1 = (1024 + tid) >> 4, cc1 = tid & 15;          // gl chunk B
  const int ff0 = tid >> 5,          dd0 = tid & 31;          // grT chunk A
  const int ff1 = 32 + (tid >> 5),   dd1 = tid & 31;          // grT chunk B

  #pragma unroll 1
  for (int t = 0; t < 12; t++) {
    // ---- per-b barrier (8 blocks): vmcnt drain + relaxed agent atomics ----
    asm volatile("s_waitcnt vmcnt(0)" ::: "memory");
    __syncthreads();
    if (tid == 0) {
      __hip_atomic_fetch_add(cntb, 1, __ATOMIC_RELAXED, __HIP_MEMORY_SCOPE_AGENT);
      const int target = (t + 1) * 8;
      while (__hip_atomic_load(cntb, __ATOMIC_RELAXED, __HIP_MEMORY_SCOPE_AGENT) < target)
        __builtin_amdgcn_s_sleep(2);
    }
    __syncthreads();

    const float* glG   = ws + OFF_GL + (t & 1) * 131072 + b * 8192;   // [j][f]
    const float* grTG  = ws + OFF_GR + (t & 1) * 131072 + b * 8192;   // [f][j]
    const float* EbO   = ws + OFF_EB + (t & 1) * 2048;
    float*       EbN   = ws + OFF_EB + ((t + 1) & 1) * 2048;
    float*       glGn  = ws + OFF_GL + ((t + 1) & 1) * 131072;
    float*       grTGn = ws + OFF_GR + ((t + 1) & 1) * 131072;

    // ---- stage panels into LDS: 4 x dwordx4 sc0 sc1 loads, then write ----
    {
      f32x4 vg0 = load_llc4(glG  + jj0 * 64  + cc0 * 4);
      f32x4 vg1 = load_llc4(glG  + jj1 * 64  + cc1 * 4);
      f32x4 vr0 = load_llc4(grTG + ff0 * 128 + dd0 * 4);
      f32x4 vr1 = load_llc4(grTG + ff1 * 128 + dd0 * 4);
      asm volatile("s_waitcnt vmcnt(0)" ::: "memory");
      __builtin_amdgcn_sched_barrier(0);
      *(f32x4*)(glS  + jj0 * 256 + ((cc0 ^ (jj0 & 15)) << 4)) = vg0;
      *(f32x4*)(glS  + jj1 * 256 + ((cc1 ^ (jj1 & 15)) << 4)) = vg1;
      *(f32x4*)(grTS + ff0 * 512 + ((dd0 ^ (ff0 & 15)) << 4)) = vr0;
      *(f32x4*)(grTS + ff1 * 512 + ((dd0 ^ (ff1 & 15)) << 4)) = vr1;
    }
    hb[lane] = gri;                        // own gr row for GAT
    __syncthreads();

    // ---- GAT logits (lane = j and j+64), mask, softmax ----
    float ev0 = 0.f, ev1 = 0.f;
    {
      const char* r0 = glS + lane * 256;
      const char* r1 = glS + (lane + 64) * 256;   // (lane+64)&15 == lane&15
      const int k = lane & 15;
      #pragma unroll
      for (int c = 0; c < 16; c++) {
        float4 hq = hb4[c];
        float4 aq = attn4[c];
        int off = (c ^ k) << 4;
        float4 g0 = *(const float4*)(r0 + off);
        float4 g1 = *(const float4*)(r1 + off);
        float v;
        v = hq.x + g0.x; ev0 += fmaxf(v, 0.2f * v) * aq.x;
        v = hq.y + g0.y; ev0 += fmaxf(v, 0.2f * v) * aq.y;
        v = hq.z + g0.z; ev0 += fmaxf(v, 0.2f * v) * aq.z;
        v = hq.w + g0.w; ev0 += fmaxf(v, 0.2f * v) * aq.w;
        v = hq.x + g1.x; ev1 += fmaxf(v, 0.2f * v) * aq.x;
        v = hq.y + g1.y; ev1 += fmaxf(v, 0.2f * v) * aq.y;
        v = hq.z + g1.z; ev1 += fmaxf(v, 0.2f * v) * aq.z;
        v = hq.w + g1.w; ev1 += fmaxf(v, 0.2f * v) * aq.w;
      }
    }
    ev0 = a0b ? ev0 : -1e20f;
    ev1 = a1b ? ev1 : -1e20f;
    float m   = wmax(fmaxf(ev0, ev1));
    float p0  = __expf(ev0 - m), p1 = __expf(ev1 - m);
    float inv = 1.f / wsum(p0 + p1);
    abuf[lane]      = p0 * inv;
    abuf[lane + 64] = p1 * inv;
    __syncthreads();

    // ---- h_temp[f=lane] = sum_j a[j] * gr[j][f] from grT LDS ----
    float ht = 0.f;
    {
      const char* rr = grTS + lane * 512;
      const int k = lane & 15;
      #pragma unroll
      for (int c = 0; c < 32; c++) {
        float4 aq = abuf4[c];
        float4 g  = *(const float4*)(rr + ((c ^ k) << 4));
        ht += aq.x * g.x + aq.y * g.y + aq.z * g.z + aq.w * g.w;
      }
    }

    float hc = fast_tanh(cebv + q0 * cew0 + q1 * cew1 + q2 * cew2);
    float hf = h_own + fast_tanh(ht) + hc;

    float xp = wsum(hf * outw) + outb;
    float d0 = wsum(hf * cdw0);
    float d1 = wsum(hf * cdw1);
    float d2 = wsum(hf * cdw2);
    float d3 = wsum(hf * cdw3);
    float al = fast_sigmoid(d0 + cdb0);
    float be = fast_sigmoid(d1 + cdb1);
    float ga = fast_sigmoid(d2 + cdb2);
    float et = fast_sigmoid(d3 + cdb3);

    float ec = 0.f;
    if (a0b) ec += load_llc(EbO + b * 128 + lane);
    if (a1b) ec += load_llc(EbO + b * 128 + lane + 64);
    ec = wsum(ec);

    float Hn = q0 - al * q0;
    float En = q1 + be * q0 - ga * q1 + 0.1f * ec;
    float Vn = q2 + et * q1 + P.noise[t * 2048 + row] * 0.01f;
    q0 = Hn; q1 = En; q2 = Vn;
    if (lane == 0) {
      store_llc(EbN + row, En);
      P.out[row * 12 + t] = (xp - abv) / awv * stdb + meanb;
      if (t == 11) {
        P.out[24576 + row * 3]     = Hn;
        P.out[24576 + row * 3 + 1] = En;
        P.out[24576 + row * 3 + 2] = Vn;
        P.out[30720 + row * 4]     = al;
        P.out[30720 + row * 4 + 1] = be;
        P.out[30720 + row * 4 + 2] = ga;
        P.out[30720 + row * 4 + 3] = et;
      }
    }

    if (t < 11) {
      // ---- incremental G: one new cnn column (window in registers) ----
      float X0 = xA, X1 = xB, X2 = xC, X3 = xp;
      xA = xB; xB = xC; xC = xp;
      float h1a = fast_tanh(b1v + w10 * X0 + w11 * X1);
      float h1c = fast_tanh(b1v + w10 * X2 + w11 * X3);
      h1b[lane * 2]     = h1a;
      h1b[lane * 2 + 1] = h1c;
      __syncthreads();
      const float* h1g = h1b + (lane >> 2) * 8;
      float a2 = b2v;
      #pragma unroll
      for (int u = 0; u < 8; u++) a2 += w2r[u] * h1g[u];
      float h2v = fast_tanh(a2);
      float g3  = wsum(w3v * h2v);
      float Gn  = fast_tanh(b3c + g3);
      if (lane == 0) hist[t] = Gn;         // own-row G history (LDS, no global)

      // h(t+1): lane 63 fresh Gn; lanes whose index crossed 253 read history
      float hnext;
      if (lane == 63) {
        hnext = Gn;
      } else {
        int gi = (t + 1) + 4 * lane;
        hnext = (gi >= 253) ? hist[gi - 253] : grow_G[gi];
      }
      __syncthreads();
      hb[lane] = hnext;
      __syncthreads();
      float glx = blv, grx = brv;
      const int k = lane & 15;
      #pragma unroll
      for (int q = 0; q < 16; q++) {
        float4 hq  = hb4[q];
        float4 wl4 = *(const float4*)(WlSc + lane * 256 + ((q ^ k) << 4));
        float4 wr4 = *(const float4*)(WrSc + lane * 256 + ((q ^ k) << 4));
        glx += hq.x * wl4.x + hq.y * wl4.y + hq.z * wl4.z + hq.w * wl4.w;
        grx += hq.x * wr4.x + hq.y * wr4.y + hq.z * wr4.z + hq.w * wr4.w;
      }
      store_llc(glGn + row * 64 + lane, glx);
      store_llc(grTGn + b * 8192 + lane * 128 + e, grx);
      gri = grx;
      h_own = hnext;
    }
  }
}

extern "C" void kernel_launch(void* const* d_in, const int* in_sizes, int n_in,
                              void* d_out, int out_size, void* d_ws, size_t ws_size,
                              hipStream_t stream) {
  Params p;
  p.x     = (const float*)d_in[0];  p.noise = (const float*)d_in[1];
  p.aw    = (const float*)d_in[2];  p.ab    = (const float*)d_in[3];
  p.pe_w1 = (const float*)d_in[4];  p.pe_b1 = (const float*)d_in[5];
  p.bn_g  = (const float*)d_in[6];  p.bn_b  = (const float*)d_in[7];
  p.bn_m  = (const float*)d_in[8];  p.bn_v  = (const float*)d_in[9];
  p.pe_w2 = (const float*)d_in[10]; p.pe_b2 = (const float*)d_in[11];
  p.w1    = (const float*)d_in[12]; p.b1    = (const float*)d_in[13];
  p.w2    = (const float*)d_in[14]; p.b2    = (const float*)d_in[15];
  p.w3    = (const float*)d_in[16]; p.b3    = (const float*)d_in[17];
  p.wl    = (const float*)d_in[18]; p.bl    = (const float*)d_in[19];
  p.wr    = (const float*)d_in[20]; p.br    = (const float*)d_in[21];
  p.attn  = (const float*)d_in[22]; p.out_w = (const float*)d_in[23];
  p.out_b = (const float*)d_in[24]; p.ce_w  = (const float*)d_in[25];
  p.ce_b  = (const float*)d_in[26]; p.cd_w  = (const float*)d_in[27];
  p.cd_b  = (const float*)d_in[28]; p.q_w   = (const float*)d_in[29];
  p.q_b   = (const float*)d_in[30]; p.k_w   = (const float*)d_in[31];
  p.k_b   = (const float*)d_in[32];
  p.ws  = (float*)d_ws;
  p.out = (float*)d_out;

  k1_h0<<<dim3(512),  dim3(256), 0, stream>>>(p);
  k2_xf<<<dim3(2048), dim3(256), 0, stream>>>(p);
  k34  <<<dim3(2560), dim3(256), 0, stream>>>(p);
  k5_adj<<<dim3(512), dim3(256), 0, stream>>>(p);
  k_scan<<<dim3(128), dim3(1024), 0, stream>>>(p);
}